// Round 1
// baseline (140.550 us; speedup 1.0000x reference)
//
#include <hip/hip_runtime.h>

#define BATCH_SZ 8192
#define MAX_HIST 200
#define EMBED_F 64

__global__ __launch_bounds__(256) void svdpp_kernel(
    const int*   __restrict__ user,
    const int*   __restrict__ item,
    const int*   __restrict__ implicit,
    const int*   __restrict__ hist_len,
    const float* __restrict__ P,
    const float* __restrict__ Q,
    const float* __restrict__ Y,
    const float* __restrict__ bu,
    const float* __restrict__ bi,
    float*       __restrict__ out)
{
    const int wave_id = (int)((blockIdx.x * blockDim.x + threadIdx.x) >> 6);
    const int lane    = (int)(threadIdx.x & 63);
    if (wave_id >= BATCH_SZ) return;
    const int b = wave_id;

    const int L = max(hist_len[b], 1);   // clamp to >=1, matches reference
    const int* idx_row = implicit + (size_t)b * MAX_HIST;

    // Lanes 0..49 each hold 4 consecutive history indices (int4) -> whole
    // 200-entry row lives in registers; broadcast via __shfl, no re-loads.
    int4 my_idx = make_int4(0, 0, 0, 0);
    if (lane < MAX_HIST / 4)
        my_idx = *reinterpret_cast<const int4*>(idx_row + lane * 4);

    float acc = 0.0f;
    int h = 0;
    // 8 independent gathers in flight per iteration for latency hiding.
    for (; h + 8 <= L; h += 8) {
        const int s0 = h >> 2, s1 = s0 + 1;
        const int i0 = __shfl(my_idx.x, s0, 64);
        const int i1 = __shfl(my_idx.y, s0, 64);
        const int i2 = __shfl(my_idx.z, s0, 64);
        const int i3 = __shfl(my_idx.w, s0, 64);
        const int i4 = __shfl(my_idx.x, s1, 64);
        const int i5 = __shfl(my_idx.y, s1, 64);
        const int i6 = __shfl(my_idx.z, s1, 64);
        const int i7 = __shfl(my_idx.w, s1, 64);
        const float y0 = Y[(size_t)i0 * EMBED_F + lane];
        const float y1 = Y[(size_t)i1 * EMBED_F + lane];
        const float y2 = Y[(size_t)i2 * EMBED_F + lane];
        const float y3 = Y[(size_t)i3 * EMBED_F + lane];
        const float y4 = Y[(size_t)i4 * EMBED_F + lane];
        const float y5 = Y[(size_t)i5 * EMBED_F + lane];
        const float y6 = Y[(size_t)i6 * EMBED_F + lane];
        const float y7 = Y[(size_t)i7 * EMBED_F + lane];
        acc += ((y0 + y1) + (y2 + y3)) + ((y4 + y5) + (y6 + y7));
    }
    for (; h < L; ++h) {
        const int s = h >> 2, c = h & 3;  // wave-uniform
        const int ix = __shfl(my_idx.x, s, 64);
        const int iy = __shfl(my_idx.y, s, 64);
        const int iz = __shfl(my_idx.z, s, 64);
        const int iw = __shfl(my_idx.w, s, 64);
        const int i  = (c == 0) ? ix : (c == 1) ? iy : (c == 2) ? iz : iw;
        acc += Y[(size_t)i * EMBED_F + lane];
    }

    const int u = user[b];
    const int it = item[b];
    const float pu = P[(size_t)u  * EMBED_F + lane];
    const float qi = Q[(size_t)it * EMBED_F + lane];
    const float norm = 1.0f / sqrtf((float)L);

    float v = pu * (qi + norm * acc);
    // 64-lane butterfly reduction
    #pragma unroll
    for (int off = 32; off > 0; off >>= 1)
        v += __shfl_xor(v, off, 64);

    if (lane == 0)
        out[b] = 3.5f + bu[u] + bi[it] + v;
}

extern "C" void kernel_launch(void* const* d_in, const int* in_sizes, int n_in,
                              void* d_out, int out_size, void* d_ws, size_t ws_size,
                              hipStream_t stream) {
    const int*   user     = (const int*)  d_in[0];
    const int*   item     = (const int*)  d_in[1];
    const int*   implicit = (const int*)  d_in[2];
    const int*   hist_len = (const int*)  d_in[3];
    const float* P        = (const float*)d_in[4];
    const float* Q        = (const float*)d_in[5];
    const float* Y        = (const float*)d_in[6];
    const float* bu       = (const float*)d_in[7];
    const float* bi       = (const float*)d_in[8];
    float* out = (float*)d_out;

    // one wave per batch element; 4 waves per block
    const int threads = 256;
    const int blocks  = BATCH_SZ / 4;  // 2048
    svdpp_kernel<<<blocks, threads, 0, stream>>>(
        user, item, implicit, hist_len, P, Q, Y, bu, bi, out);
}

// Round 2
// 138.914 us; speedup vs baseline: 1.0118x; 1.0118x over previous
//
#include <hip/hip_runtime.h>

#define BATCH_SZ 8192
#define MAX_HIST 200
#define EMBED_F 64

__device__ __forceinline__ float4 f4add(float4 a, float4 b) {
    return make_float4(a.x + b.x, a.y + b.y, a.z + b.z, a.w + b.w);
}

// One 64-lane wave per batch element.
// lane l: g = l>>4 selects one of 4 history rows in a pack,
//         s = l&15 selects the float4 column within the 64-float row.
// One global_load_dwordx4 per lane => 4 full Y rows (1 KiB) per instruction.
__global__ __launch_bounds__(256) void svdpp_kernel(
    const int*   __restrict__ user,
    const int*   __restrict__ item,
    const int*   __restrict__ implicit,
    const int*   __restrict__ hist_len,
    const float* __restrict__ P,
    const float* __restrict__ Q,
    const float* __restrict__ Y,
    const float* __restrict__ bu,
    const float* __restrict__ bi,
    float*       __restrict__ out)
{
    __shared__ int lds_idx[4][MAX_HIST];   // per-wave index cache (4 waves/block)

    const int wblk = (int)(threadIdx.x >> 6);          // wave within block
    const int b    = (int)(blockIdx.x * 4 + wblk);     // batch element
    const int lane = (int)(threadIdx.x & 63);
    const int g = lane >> 4;
    const int s = lane & 15;

    const int L = max(hist_len[b], 1);

    // Stage this wave's 200 indices into LDS (lanes 0..49, int4 each).
    const int* idx_row = implicit + (size_t)b * MAX_HIST;
    if (lane < MAX_HIST / 4) {
        int4 v = *reinterpret_cast<const int4*>(idx_row + lane * 4);
        *reinterpret_cast<int4*>(&lds_idx[wblk][lane * 4]) = v;
    }
    __syncthreads();

    const int* myidx = lds_idx[wblk];
    const float4* __restrict__ Y4 = reinterpret_cast<const float4*>(Y);

    float4 acc = make_float4(0.f, 0.f, 0.f, 0.f);
    int h = 0;

    // Main loop: 32 rows per iteration, 8 dwordx4 loads in flight.
    for (; h + 32 <= L; h += 32) {
        const int i0 = myidx[h      + g];
        const int i1 = myidx[h + 4  + g];
        const int i2 = myidx[h + 8  + g];
        const int i3 = myidx[h + 12 + g];
        const int i4 = myidx[h + 16 + g];
        const int i5 = myidx[h + 20 + g];
        const int i6 = myidx[h + 24 + g];
        const int i7 = myidx[h + 28 + g];
        const float4 y0 = Y4[(size_t)i0 * 16 + s];
        const float4 y1 = Y4[(size_t)i1 * 16 + s];
        const float4 y2 = Y4[(size_t)i2 * 16 + s];
        const float4 y3 = Y4[(size_t)i3 * 16 + s];
        const float4 y4 = Y4[(size_t)i4 * 16 + s];
        const float4 y5 = Y4[(size_t)i5 * 16 + s];
        const float4 y6 = Y4[(size_t)i6 * 16 + s];
        const float4 y7 = Y4[(size_t)i7 * 16 + s];
        acc = f4add(acc, f4add(f4add(f4add(y0, y1), f4add(y2, y3)),
                               f4add(f4add(y4, y5), f4add(y6, y7))));
    }
    // Middle tier: 16 rows per iteration, fully valid.
    for (; h + 16 <= L; h += 16) {
        const int i0 = myidx[h      + g];
        const int i1 = myidx[h + 4  + g];
        const int i2 = myidx[h + 8  + g];
        const int i3 = myidx[h + 12 + g];
        const float4 y0 = Y4[(size_t)i0 * 16 + s];
        const float4 y1 = Y4[(size_t)i1 * 16 + s];
        const float4 y2 = Y4[(size_t)i2 * 16 + s];
        const float4 y3 = Y4[(size_t)i3 * 16 + s];
        acc = f4add(acc, f4add(f4add(y0, y1), f4add(y2, y3)));
    }
    // Tail: 4 rows per iteration, per-group predicate on the add.
    // Loads are always in-bounds: h+g <= 4*floor((L-1)/4)+3 <= 199 < MAX_HIST,
    // and every implicit[] slot holds a valid item id (mask only zeroes them).
    for (; h < L; h += 4) {
        const int i = myidx[h + g];
        const float4 y = Y4[(size_t)i * 16 + s];
        if (h + g < L) acc = f4add(acc, y);
    }

    // Reduce acc across the 4 groups (lanes differing in bits 4/5).
    #pragma unroll
    for (int off = 16; off < 64; off <<= 1) {
        acc.x += __shfl_xor(acc.x, off, 64);
        acc.y += __shfl_xor(acc.y, off, 64);
        acc.z += __shfl_xor(acc.z, off, 64);
        acc.w += __shfl_xor(acc.w, off, 64);
    }
    // Now every lane holds the full y_sum for its column s.

    const int u  = user[b];
    const int it = item[b];
    const float4 pu = reinterpret_cast<const float4*>(P)[(size_t)u  * 16 + s];
    const float4 qi = reinterpret_cast<const float4*>(Q)[(size_t)it * 16 + s];
    const float norm = 1.0f / sqrtf((float)L);

    float v = pu.x * (qi.x + norm * acc.x)
            + pu.y * (qi.y + norm * acc.y)
            + pu.z * (qi.z + norm * acc.z)
            + pu.w * (qi.w + norm * acc.w);

    // Reduce over the 16 column-lanes.
    #pragma unroll
    for (int off = 1; off < 16; off <<= 1)
        v += __shfl_xor(v, off, 64);

    if (lane == 0)
        out[b] = 3.5f + bu[u] + bi[it] + v;
}

extern "C" void kernel_launch(void* const* d_in, const int* in_sizes, int n_in,
                              void* d_out, int out_size, void* d_ws, size_t ws_size,
                              hipStream_t stream) {
    const int*   user     = (const int*)  d_in[0];
    const int*   item     = (const int*)  d_in[1];
    const int*   implicit = (const int*)  d_in[2];
    const int*   hist_len = (const int*)  d_in[3];
    const float* P        = (const float*)d_in[4];
    const float* Q        = (const float*)d_in[5];
    const float* Y        = (const float*)d_in[6];
    const float* bu       = (const float*)d_in[7];
    const float* bi       = (const float*)d_in[8];
    float* out = (float*)d_out;

    const int threads = 256;                 // 4 waves/block
    const int blocks  = BATCH_SZ / 4;        // 2048
    svdpp_kernel<<<blocks, threads, 0, stream>>>(
        user, item, implicit, hist_len, P, Q, Y, bu, bi, out);
}

// Round 3
// 135.900 us; speedup vs baseline: 1.0342x; 1.0222x over previous
//
#include <hip/hip_runtime.h>

#define BATCH_SZ 8192
#define MAX_HIST 200
#define EMBED_F 64

__device__ __forceinline__ float4 f4add(float4 a, float4 b) {
    return make_float4(a.x + b.x, a.y + b.y, a.z + b.z, a.w + b.w);
}

// One 64-lane wave per batch element.
// lane l: g = l>>4 selects one of 4 history rows in a pack,
//         s = l&15 selects the float4 column within the 64-float row.
// One global_load_dwordx4 per lane => 4 full Y rows (1 KiB) per instruction.
// Main loop keeps 16 such loads (64 rows, 16 KiB) in flight per wave.
__global__ __launch_bounds__(256) void svdpp_kernel(
    const int*   __restrict__ user,
    const int*   __restrict__ item,
    const int*   __restrict__ implicit,
    const int*   __restrict__ hist_len,
    const float* __restrict__ P,
    const float* __restrict__ Q,
    const float* __restrict__ Y,
    const float* __restrict__ bu,
    const float* __restrict__ bi,
    float*       __restrict__ out)
{
    __shared__ int lds_idx[4][MAX_HIST];   // per-wave index cache (4 waves/block)

    const int wblk = (int)(threadIdx.x >> 6);          // wave within block
    const int b    = (int)(blockIdx.x * 4 + wblk);     // batch element
    const int lane = (int)(threadIdx.x & 63);
    const int g = lane >> 4;
    const int s = lane & 15;

    const int L = max(hist_len[b], 1);

    // Hoisted epilogue gathers — issue early, consumed after the gather loop.
    const int u  = user[b];
    const int it = item[b];
    const float4 pu = reinterpret_cast<const float4*>(P)[(size_t)u  * 16 + s];
    const float4 qi = reinterpret_cast<const float4*>(Q)[(size_t)it * 16 + s];
    const float bub = bu[u];
    const float bib = bi[it];

    // Stage this wave's 200 indices into LDS (lanes 0..49, int4 each).
    const int* idx_row = implicit + (size_t)b * MAX_HIST;
    if (lane < MAX_HIST / 4) {
        int4 v = *reinterpret_cast<const int4*>(idx_row + lane * 4);
        *reinterpret_cast<int4*>(&lds_idx[wblk][lane * 4]) = v;
    }
    __syncthreads();

    const int* myidx = lds_idx[wblk];
    const float4* __restrict__ Y4 = reinterpret_cast<const float4*>(Y);

    float4 acc = make_float4(0.f, 0.f, 0.f, 0.f);
    int h = 0;

    // Main loop: 64 rows per iteration, 16 dwordx4 loads in flight.
    for (; h + 64 <= L; h += 64) {
        float4 y[16];
        #pragma unroll
        for (int j = 0; j < 16; ++j) {
            const int i = myidx[h + j * 4 + g];
            y[j] = Y4[(size_t)i * 16 + s];
        }
        float4 t0 = f4add(f4add(f4add(y[0], y[1]),  f4add(y[2], y[3])),
                          f4add(f4add(y[4], y[5]),  f4add(y[6], y[7])));
        float4 t1 = f4add(f4add(f4add(y[8], y[9]),  f4add(y[10], y[11])),
                          f4add(f4add(y[12], y[13]), f4add(y[14], y[15])));
        acc = f4add(acc, f4add(t0, t1));
    }
    // Middle tier: 16 rows per iteration, fully valid.
    for (; h + 16 <= L; h += 16) {
        const int i0 = myidx[h      + g];
        const int i1 = myidx[h + 4  + g];
        const int i2 = myidx[h + 8  + g];
        const int i3 = myidx[h + 12 + g];
        const float4 y0 = Y4[(size_t)i0 * 16 + s];
        const float4 y1 = Y4[(size_t)i1 * 16 + s];
        const float4 y2 = Y4[(size_t)i2 * 16 + s];
        const float4 y3 = Y4[(size_t)i3 * 16 + s];
        acc = f4add(acc, f4add(f4add(y0, y1), f4add(y2, y3)));
    }
    // Tail: 4 rows per iteration, per-group predicate on the add.
    // Loads always in-bounds: h+g <= 199 < MAX_HIST, and every implicit[]
    // slot holds a valid item id (the mask only zeroes them in the ref).
    for (; h < L; h += 4) {
        const int i = myidx[h + g];
        const float4 y = Y4[(size_t)i * 16 + s];
        if (h + g < L) acc = f4add(acc, y);
    }

    // Reduce acc across the 4 row-groups (lanes differing in bits 4/5).
    #pragma unroll
    for (int off = 16; off < 64; off <<= 1) {
        acc.x += __shfl_xor(acc.x, off, 64);
        acc.y += __shfl_xor(acc.y, off, 64);
        acc.z += __shfl_xor(acc.z, off, 64);
        acc.w += __shfl_xor(acc.w, off, 64);
    }
    // Every lane now holds the full y_sum for its column s.

    const float norm = 1.0f / sqrtf((float)L);
    float v = pu.x * (qi.x + norm * acc.x)
            + pu.y * (qi.y + norm * acc.y)
            + pu.z * (qi.z + norm * acc.z)
            + pu.w * (qi.w + norm * acc.w);

    // Reduce over the 16 column-lanes.
    #pragma unroll
    for (int off = 1; off < 16; off <<= 1)
        v += __shfl_xor(v, off, 64);

    if (lane == 0)
        out[b] = 3.5f + bub + bib + v;
}

extern "C" void kernel_launch(void* const* d_in, const int* in_sizes, int n_in,
                              void* d_out, int out_size, void* d_ws, size_t ws_size,
                              hipStream_t stream) {
    const int*   user     = (const int*)  d_in[0];
    const int*   item     = (const int*)  d_in[1];
    const int*   implicit = (const int*)  d_in[2];
    const int*   hist_len = (const int*)  d_in[3];
    const float* P        = (const float*)d_in[4];
    const float* Q        = (const float*)d_in[5];
    const float* Y        = (const float*)d_in[6];
    const float* bu       = (const float*)d_in[7];
    const float* bi       = (const float*)d_in[8];
    float* out = (float*)d_out;

    const int threads = 256;                 // 4 waves/block
    const int blocks  = BATCH_SZ / 4;        // 2048
    svdpp_kernel<<<blocks, threads, 0, stream>>>(
        user, item, implicit, hist_len, P, Q, Y, bu, bi, out);
}

// Round 4
// 135.575 us; speedup vs baseline: 1.0367x; 1.0024x over previous
//
#include <hip/hip_runtime.h>

#define BATCH_SZ 8192
#define MAX_HIST 200
#define EMBED_F 64

__device__ __forceinline__ float4 f4add(float4 a, float4 b) {
    return make_float4(a.x + b.x, a.y + b.y, a.z + b.z, a.w + b.w);
}

// One batch element per 128-thread block (2 waves). History rows are grouped
// into 4-row packs; wave w processes packs p with (p & 1) == w — halves the
// worst-case per-wave work (load balance) vs one wave per element.
// Within a wave: lane l -> g = l>>4 picks the row within a pack, s = l&15
// picks the float4 column. One global_load_dwordx4 = 4 full Y rows (1 KiB).
__global__ __launch_bounds__(128) void svdpp_kernel(
    const int*   __restrict__ user,
    const int*   __restrict__ item,
    const int*   __restrict__ implicit,
    const int*   __restrict__ hist_len,
    const float* __restrict__ P,
    const float* __restrict__ Q,
    const float* __restrict__ Y,
    const float* __restrict__ bu,
    const float* __restrict__ bi,
    float*       __restrict__ out)
{
    __shared__ int    lds_idx[MAX_HIST];
    __shared__ float4 lds_part[16];

    const int b    = (int)blockIdx.x;
    const int w    = (int)(threadIdx.x >> 6);   // wave 0 or 1
    const int lane = (int)(threadIdx.x & 63);
    const int g = lane >> 4;
    const int s = lane & 15;

    const int L = max(hist_len[b], 1);

    // Wave 0 hoists the epilogue gathers early (overlap with the loop).
    int u = 0, it = 0;
    float4 pu = make_float4(0.f, 0.f, 0.f, 0.f);
    float4 qi = make_float4(0.f, 0.f, 0.f, 0.f);
    float bub = 0.f, bib = 0.f;
    if (w == 0) {
        u  = user[b];
        it = item[b];
        pu = reinterpret_cast<const float4*>(P)[(size_t)u  * 16 + s];
        qi = reinterpret_cast<const float4*>(Q)[(size_t)it * 16 + s];
        bub = bu[u];
        bib = bi[it];
    }

    // Stage the element's 200 indices into LDS (threads 0..49, int4 each).
    const int* idx_row = implicit + (size_t)b * MAX_HIST;
    if (threadIdx.x < MAX_HIST / 4) {
        int4 v = *reinterpret_cast<const int4*>(idx_row + threadIdx.x * 4);
        *reinterpret_cast<int4*>(&lds_idx[threadIdx.x * 4]) = v;
    }
    __syncthreads();

    const float4* __restrict__ Y4 = reinterpret_cast<const float4*>(Y);

    const int full   = L >> 2;         // count of fully-valid packs
    const int npacks = (L + 3) >> 2;   // total packs incl. partial

    float4 acc = make_float4(0.f, 0.f, 0.f, 0.f);
    int p = w;

    // Main loop: 8 packs (32 rows, 8 KiB) in flight per iteration.
    for (; p + 14 < full; p += 16) {
        float4 y[8];
        #pragma unroll
        for (int j = 0; j < 8; ++j) {
            const int i = lds_idx[4 * (p + 2 * j) + g];
            y[j] = Y4[(size_t)i * 16 + s];
        }
        acc = f4add(acc, f4add(f4add(f4add(y[0], y[1]), f4add(y[2], y[3])),
                               f4add(f4add(y[4], y[5]), f4add(y[6], y[7]))));
    }
    // Mid tier: 4 packs in flight.
    for (; p + 6 < full; p += 8) {
        float4 y[4];
        #pragma unroll
        for (int j = 0; j < 4; ++j) {
            const int i = lds_idx[4 * (p + 2 * j) + g];
            y[j] = Y4[(size_t)i * 16 + s];
        }
        acc = f4add(acc, f4add(f4add(y[0], y[1]), f4add(y[2], y[3])));
    }
    // Tail: one pack at a time, predicate the add only. Load is always
    // in-bounds: 4p+g <= 4*(npacks-1)+3 <= 199 < MAX_HIST, and every
    // implicit[] slot holds a valid item id (ref mask only zeroes them).
    for (; p < npacks; p += 2) {
        const int i = lds_idx[4 * p + g];
        const float4 y = Y4[(size_t)i * 16 + s];
        if (4 * p + g < L) acc = f4add(acc, y);
    }

    // Reduce over the 4 row-groups within this wave (bits 4,5 of lane).
    #pragma unroll
    for (int off = 16; off < 64; off <<= 1) {
        acc.x += __shfl_xor(acc.x, off, 64);
        acc.y += __shfl_xor(acc.y, off, 64);
        acc.z += __shfl_xor(acc.z, off, 64);
        acc.w += __shfl_xor(acc.w, off, 64);
    }

    // Wave 1 publishes its partial; wave 0 combines and finishes.
    if (w == 1 && lane < 16) lds_part[s] = acc;
    __syncthreads();
    if (w == 0) {
        const float4 o = lds_part[s];
        acc = f4add(acc, o);

        const float norm = 1.0f / sqrtf((float)L);
        float v = pu.x * (qi.x + norm * acc.x)
                + pu.y * (qi.y + norm * acc.y)
                + pu.z * (qi.z + norm * acc.z)
                + pu.w * (qi.w + norm * acc.w);

        #pragma unroll
        for (int off = 1; off < 16; off <<= 1)
            v += __shfl_xor(v, off, 64);

        if (lane == 0)
            out[b] = 3.5f + bub + bib + v;
    }
}

extern "C" void kernel_launch(void* const* d_in, const int* in_sizes, int n_in,
                              void* d_out, int out_size, void* d_ws, size_t ws_size,
                              hipStream_t stream) {
    const int*   user     = (const int*)  d_in[0];
    const int*   item     = (const int*)  d_in[1];
    const int*   implicit = (const int*)  d_in[2];
    const int*   hist_len = (const int*)  d_in[3];
    const float* P        = (const float*)d_in[4];
    const float* Q        = (const float*)d_in[5];
    const float* Y        = (const float*)d_in[6];
    const float* bu       = (const float*)d_in[7];
    const float* bi       = (const float*)d_in[8];
    float* out = (float*)d_out;

    svdpp_kernel<<<BATCH_SZ, 128, 0, stream>>>(
        user, item, implicit, hist_len, P, Q, Y, bu, bi, out);
}